// Round 1
// baseline (47113.608 us; speedup 1.0000x reference)
//
#include <hip/hip_runtime.h>

#define D_   1024
#define H_   16
#define HD_  64
#define T_   1024
#define B_   2
#define L_   24
#define V_   50257
#define BT_  (B_ * T_)   // 2048 tokens

typedef __bf16 bf16x8 __attribute__((ext_vector_type(8)));
typedef __bf16 bf16x4 __attribute__((ext_vector_type(4)));
typedef float  f32x4  __attribute__((ext_vector_type(4)));

__device__ __forceinline__ float gelu_f(float x) {
    // tanh-approx GELU, matching jax.nn.gelu(approximate=True)
    float u = 0.7978845608028654f * (x + 0.044715f * x * x * x);
    float t = __expf(2.0f * u);          // overflow -> inf -> th=1 (stable)
    float th = 1.0f - 2.0f / (t + 1.0f); // tanh(u)
    return 0.5f * x * (1.0f + th);
}

// ---------------------------------------------------------------------------
// Generic bf16-MFMA GEMM: C[M,N] = epi(A[M,K] @ B + bias + res)
//   TRB=false: B is [K,N] row-major (ldb = row stride)
//   TRB=true : B is [N,K] row-major (ldb = row stride)  (B^T GEMM)
// fp32 inputs converted to bf16 at LDS staging; fp32 accumulate.
// Batched via gridDim.z: per-z offsets  (z/H_)*s?1 + (z%H_)*s?2.
// MASK: scale then causal mask (col > row -> -1e30), row/col within batch.
// ---------------------------------------------------------------------------
template<int BM, int BN, int WR, int WC, bool TRB, bool BIAS, bool RES, bool GELU, bool MASK>
__global__ __launch_bounds__(256) void gemm_k(
    const float* __restrict__ A, const float* __restrict__ Bm,
    const float* __restrict__ bias, const float* __restrict__ res,
    float* __restrict__ C,
    int M, int N, int K, int lda, int ldb, int ldc,
    long sA1, long sA2, long sB1, long sB2, long sC1, long sC2,
    float scale)
{
    constexpr int BK = 32;
    constexpr int LS = BK + 8;               // padded LDS row stride (bf16 elems)
    constexpr int TM = BM / (WR * 16);
    constexpr int TN = BN / (WC * 16);
    __shared__ __bf16 As[BM * LS];
    __shared__ __bf16 Bs[BN * LS];

    const int z  = blockIdx.z;
    const int zb = z / H_, zh = z % H_;
    A  += (long)zb * sA1 + (long)zh * sA2;
    Bm += (long)zb * sB1 + (long)zh * sB2;
    C  += (long)zb * sC1 + (long)zh * sC2;

    const int bm   = blockIdx.y * BM;
    const int bn   = blockIdx.x * BN;
    const int tid  = threadIdx.x;
    const int wave = tid >> 6, lane = tid & 63;
    const int wm   = (wave / WC) * (TM * 16);
    const int wn   = (wave % WC) * (TN * 16);
    const int mr   = lane & 15;
    const int kg   = (lane >> 4) * 8;

    f32x4 acc[TM][TN];
#pragma unroll
    for (int i = 0; i < TM; i++)
#pragma unroll
        for (int j = 0; j < TN; j++)
            acc[i][j] = (f32x4){0.f, 0.f, 0.f, 0.f};

    for (int k0 = 0; k0 < K; k0 += BK) {
        // ---- stage A tile [BM x BK] -> As[m][k] ----
#pragma unroll
        for (int q = tid; q < BM * (BK / 4); q += 256) {
            int r = q >> 3, c = (q & 7) * 4;
            const float4 v = *(const float4*)&A[(long)(bm + r) * lda + k0 + c];
            bf16x4 w;
            w[0] = (__bf16)v.x; w[1] = (__bf16)v.y;
            w[2] = (__bf16)v.z; w[3] = (__bf16)v.w;
            *(bf16x4*)&As[r * LS + c] = w;
        }
        // ---- stage B tile -> Bs[n][k] ----
        if constexpr (TRB) {
#pragma unroll
            for (int q = tid; q < BN * (BK / 4); q += 256) {
                int r = q >> 3, c = (q & 7) * 4;
                bf16x4 w;
                if (bn + r < N) {
                    const float4 v = *(const float4*)&Bm[(long)(bn + r) * ldb + k0 + c];
                    w[0] = (__bf16)v.x; w[1] = (__bf16)v.y;
                    w[2] = (__bf16)v.z; w[3] = (__bf16)v.w;
                } else {
                    w[0] = (__bf16)0.f; w[1] = (__bf16)0.f;
                    w[2] = (__bf16)0.f; w[3] = (__bf16)0.f;
                }
                *(bf16x4*)&Bs[r * LS + c] = w;
            }
        } else {
            // B is [K,N]: each work-item gathers 8 k's of one n (coalesced along n)
#pragma unroll
            for (int it = tid; it < (BK / 8) * BN; it += 256) {
                int n = it & (BN - 1), g = it / BN;
                int gn = bn + n;
                float vv[8];
#pragma unroll
                for (int j = 0; j < 8; j++)
                    vv[j] = (gn < N) ? Bm[(long)(k0 + g * 8 + j) * ldb + gn] : 0.f;
                bf16x8 w;
#pragma unroll
                for (int j = 0; j < 8; j++) w[j] = (__bf16)vv[j];
                *(bf16x8*)&Bs[n * LS + g * 8] = w;
            }
        }
        __syncthreads();

        bf16x8 af[TM], bfr[TN];
#pragma unroll
        for (int i = 0; i < TM; i++)
            af[i] = *(const bf16x8*)&As[(wm + i * 16 + mr) * LS + kg];
#pragma unroll
        for (int j = 0; j < TN; j++)
            bfr[j] = *(const bf16x8*)&Bs[(wn + j * 16 + mr) * LS + kg];
#pragma unroll
        for (int i = 0; i < TM; i++)
#pragma unroll
            for (int j = 0; j < TN; j++)
                acc[i][j] = __builtin_amdgcn_mfma_f32_16x16x32_bf16(
                    af[i], bfr[j], acc[i][j], 0, 0, 0);
        __syncthreads();
    }

    // ---- epilogue: C/D layout col=lane&15, row=(lane>>4)*4+r  (m89-verified) ----
#pragma unroll
    for (int i = 0; i < TM; i++) {
#pragma unroll
        for (int j = 0; j < TN; j++) {
#pragma unroll
            for (int r = 0; r < 4; r++) {
                int row = bm + wm + i * 16 + (lane >> 4) * 4 + r;
                int col = bn + wn + j * 16 + mr;
                float v = acc[i][j][r];
                if constexpr (MASK) { v *= scale; if (col > row) v = -1e30f; }
                if constexpr (BIAS) v += bias[col];
                if constexpr (GELU) v = gelu_f(v);
                if constexpr (RES)  v += res[(long)row * ldc + col];
                if (col < N) C[(long)row * ldc + col] = v;
            }
        }
    }
}

// ---------------------------------------------------------------------------
// x[tok] = wte[idx[tok]] + wpe[tok % T]
// ---------------------------------------------------------------------------
__global__ __launch_bounds__(256) void embed_k(
    const int* __restrict__ idx, const float* __restrict__ wte,
    const float* __restrict__ wpe, float* __restrict__ x)
{
    const int tok = blockIdx.x;
    const int t   = tok & (T_ - 1);
    const int id  = idx[tok];
    const int c   = threadIdx.x * 4;
    const float4 a = *(const float4*)&wte[(long)id * D_ + c];
    const float4 p = *(const float4*)&wpe[(long)t * D_ + c];
    float4 o;
    o.x = a.x + p.x; o.y = a.y + p.y; o.z = a.z + p.z; o.w = a.w + p.w;
    *(float4*)&x[(long)tok * D_ + c] = o;
}

// ---------------------------------------------------------------------------
// LayerNorm over last dim (D=1024), one block per row, fp32 in/out
// ---------------------------------------------------------------------------
__global__ __launch_bounds__(256) void ln_k(
    const float* __restrict__ x, const float* __restrict__ w,
    const float* __restrict__ b, float* __restrict__ out)
{
    const int row = blockIdx.x;
    const int tid = threadIdx.x;
    const float4 v = *(const float4*)&x[(long)row * D_ + tid * 4];
    float s  = v.x + v.y + v.z + v.w;
    float s2 = v.x * v.x + v.y * v.y + v.z * v.z + v.w * v.w;
#pragma unroll
    for (int o = 32; o > 0; o >>= 1) {
        s  += __shfl_down(s, o);
        s2 += __shfl_down(s2, o);
    }
    __shared__ float rs[4], rs2[4];
    if ((tid & 63) == 0) { rs[tid >> 6] = s; rs2[tid >> 6] = s2; }
    __syncthreads();
    const float S1 = rs[0] + rs[1] + rs[2] + rs[3];
    const float S2 = rs2[0] + rs2[1] + rs2[2] + rs2[3];
    const float mean = S1 * (1.f / D_);
    const float var  = S2 * (1.f / D_) - mean * mean;
    const float rstd = rsqrtf(var + 1e-5f);
    const float4 wv = *(const float4*)&w[tid * 4];
    const float4 bv = *(const float4*)&b[tid * 4];
    float4 o;
    o.x = (v.x - mean) * rstd * wv.x + bv.x;
    o.y = (v.y - mean) * rstd * wv.y + bv.y;
    o.z = (v.z - mean) * rstd * wv.z + bv.z;
    o.w = (v.w - mean) * rstd * wv.w + bv.w;
    *(float4*)&out[(long)row * D_ + tid * 4] = o;
}

// ---------------------------------------------------------------------------
// Row softmax over T_ entries (masked entries hold -1e30), in place
// ---------------------------------------------------------------------------
__global__ __launch_bounds__(256) void softmax_k(float* __restrict__ S)
{
    const long row = blockIdx.x;
    float* p = S + row * T_;
    const int tid = threadIdx.x;
    float4 v = *(const float4*)&p[tid * 4];
    float mx = fmaxf(fmaxf(v.x, v.y), fmaxf(v.z, v.w));
#pragma unroll
    for (int o = 32; o > 0; o >>= 1) mx = fmaxf(mx, __shfl_down(mx, o));
    __shared__ float rm[4], rsum[4];
    if ((tid & 63) == 0) rm[tid >> 6] = mx;
    __syncthreads();
    mx = fmaxf(fmaxf(rm[0], rm[1]), fmaxf(rm[2], rm[3]));
    v.x = __expf(v.x - mx);
    v.y = __expf(v.y - mx);
    v.z = __expf(v.z - mx);
    v.w = __expf(v.w - mx);
    float s = v.x + v.y + v.z + v.w;
#pragma unroll
    for (int o = 32; o > 0; o >>= 1) s += __shfl_down(s, o);
    if ((tid & 63) == 0) rsum[tid >> 6] = s;
    __syncthreads();
    const float inv = 1.f / (rsum[0] + rsum[1] + rsum[2] + rsum[3]);
    v.x *= inv; v.y *= inv; v.z *= inv; v.w *= inv;
    *(float4*)&p[tid * 4] = v;
}

// ---------------------------------------------------------------------------
extern "C" void kernel_launch(void* const* d_in, const int* in_sizes, int n_in,
                              void* d_out, int out_size, void* d_ws, size_t ws_size,
                              hipStream_t stream)
{
    const int*   idx   = (const int*)  d_in[0];
    const float* wte   = (const float*)d_in[1];
    const float* wpe   = (const float*)d_in[2];
    const float* ln1w  = (const float*)d_in[3];
    const float* ln1b  = (const float*)d_in[4];
    const float* attnw = (const float*)d_in[5];
    const float* attnb = (const float*)d_in[6];
    const float* apw   = (const float*)d_in[7];
    const float* apb   = (const float*)d_in[8];
    const float* ln2w  = (const float*)d_in[9];
    const float* ln2b  = (const float*)d_in[10];
    const float* fcw   = (const float*)d_in[11];
    const float* fcb   = (const float*)d_in[12];
    const float* prw   = (const float*)d_in[13];
    const float* prb   = (const float*)d_in[14];
    const float* lnfw  = (const float*)d_in[15];
    const float* lnfb  = (const float*)d_in[16];
    float* out = (float*)d_out;

    // workspace layout (fp32), total ~208 MB
    float* ws  = (float*)d_ws;
    float* x   = ws;                          // [2048,1024]   residual stream
    float* h   = x   + (long)BT_ * D_;        // [2048,1024]   LN output
    float* qkv = h   + (long)BT_ * D_;        // [2048,3072]
    float* y   = qkv + (long)BT_ * 3 * D_;    // [2048,1024]   attn out
    float* h2  = y   + (long)BT_ * D_;        // [2048,4096]   MLP hidden
    float* Sb  = h2  + (long)BT_ * 4 * D_;    // [32,1024,1024] scores

    embed_k<<<BT_, 256, 0, stream>>>(idx, wte, wpe, x);

    const float iscale = 0.125f;  // 1/sqrt(HD)

    for (int l = 0; l < L_; l++) {
        // ln1
        ln_k<<<BT_, 256, 0, stream>>>(x, ln1w + (long)l * D_, ln1b + (long)l * D_, h);

        // qkv = h @ attn_w + attn_b       [2048,3072]
        gemm_k<128,128,2,2,false,true,false,false,false>
            <<<dim3(3 * D_ / 128, BT_ / 128, 1), 256, 0, stream>>>(
            h, attnw + (long)l * D_ * 3 * D_, attnb + (long)l * 3 * D_, nullptr, qkv,
            BT_, 3 * D_, D_, D_, 3 * D_, 3 * D_,
            0, 0, 0, 0, 0, 0, 1.f);

        // S = scale * Q @ K^T, causal-masked   batched over 32 (b,h)
        gemm_k<128,128,2,2,true,false,false,false,true>
            <<<dim3(T_ / 128, T_ / 128, B_ * H_), 256, 0, stream>>>(
            qkv, qkv + D_, nullptr, nullptr, Sb,
            T_, T_, HD_, 3 * D_, 3 * D_, T_,
            (long)T_ * 3 * D_, HD_, (long)T_ * 3 * D_, HD_,
            (long)H_ * T_ * T_, (long)T_ * T_, iscale);

        softmax_k<<<B_ * H_ * T_, 256, 0, stream>>>(Sb);

        // y = P @ V   (writes [B,T,H,HD] = [2048,1024] interleaved by head)
        gemm_k<128,64,2,2,false,false,false,false,false>
            <<<dim3(1, T_ / 128, B_ * H_), 256, 0, stream>>>(
            Sb, qkv + 2 * D_, nullptr, nullptr, y,
            T_, HD_, T_, T_, 3 * D_, D_,
            (long)H_ * T_ * T_, (long)T_ * T_, (long)T_ * 3 * D_, HD_,
            (long)T_ * D_, HD_, 1.f);

        // x = x + y @ attnproj_w + attnproj_b
        gemm_k<128,128,2,2,false,true,true,false,false>
            <<<dim3(D_ / 128, BT_ / 128, 1), 256, 0, stream>>>(
            y, apw + (long)l * D_ * D_, apb + (long)l * D_, x, x,
            BT_, D_, D_, D_, D_, D_,
            0, 0, 0, 0, 0, 0, 1.f);

        // ln2
        ln_k<<<BT_, 256, 0, stream>>>(x, ln2w + (long)l * D_, ln2b + (long)l * D_, h);

        // h2 = gelu(h @ fc_w + fc_b)     [2048,4096]
        gemm_k<128,128,2,2,false,true,false,true,false>
            <<<dim3(4 * D_ / 128, BT_ / 128, 1), 256, 0, stream>>>(
            h, fcw + (long)l * D_ * 4 * D_, fcb + (long)l * 4 * D_, nullptr, h2,
            BT_, 4 * D_, D_, D_, 4 * D_, 4 * D_,
            0, 0, 0, 0, 0, 0, 1.f);

        // x = x + h2 @ proj_w + proj_b
        gemm_k<128,128,2,2,false,true,true,false,false>
            <<<dim3(D_ / 128, BT_ / 128, 1), 256, 0, stream>>>(
            h2, prw + (long)l * 4 * D_ * D_, prb + (long)l * D_, x, x,
            BT_, D_, 4 * D_, 4 * D_, D_, D_,
            0, 0, 0, 0, 0, 0, 1.f);
    }

    // final LN
    ln_k<<<BT_, 256, 0, stream>>>(x, lnfw, lnfb, h);

    // logits = h @ wte^T   [2048, 50257]
    gemm_k<128,128,2,2,true,false,false,false,false>
        <<<dim3((V_ + 127) / 128, BT_ / 128, 1), 256, 0, stream>>>(
        h, wte, nullptr, nullptr, out,
        BT_, V_, D_, D_, D_, V_,
        0, 0, 0, 0, 0, 0, 1.f);
}